// Round 2
// baseline (984.675 us; speedup 1.0000x reference)
//
#include <hip/hip_runtime.h>

// Problem: B=8, NQ=1024, NC=4096, D=256, C+1=25. ALL float I/O is FP32
// (threshold analysis: no bf16 floor applied => fp32 dataset). labels int32.
// Strategy: split-precision bf16 MFMA (hi+lo, 3-term) for emb GEMM and QK^T;
// single bf16 MFMA for P@[c_emb|onehot]. Flash-style online softmax, NC split
// across blocks (runtime nsplit chosen from ws_size).

typedef __attribute__((ext_vector_type(8))) short short8;
typedef __attribute__((ext_vector_type(4))) float floatx4;

#define WB 8
#define WNQ 1024
#define WNC 4096
#define NROWS 8192          // B*NQ

static __device__ __forceinline__ float bf2f(unsigned short u) {
    union { unsigned int i; float f; } v; v.i = ((unsigned int)u) << 16; return v.f;
}
static __device__ __forceinline__ unsigned short f2bf(float f) {
    union { float ff; unsigned int i; } v; v.ff = f;
    return (unsigned short)((v.i + 0x7FFFu + ((v.i >> 16) & 1u)) >> 16);
}
static __device__ __forceinline__ void split2(float x, unsigned short& h, unsigned short& l) {
    h = f2bf(x);
    l = f2bf(x - bf2f(h));
}
static __device__ __forceinline__ float logsig(float x) {
    return (x >= 0.f) ? -log1pf(__expf(-x)) : x - log1pf(__expf(x));
}

union V16 { int4 v; short8 s8; unsigned short s[8]; };
union F8  { float4 v[2]; float f[8]; };

// ---------------------------------------------------------------------------
// emb = concat(head,tail) @ W_rel + b_rel (fp32 in) -> bf16 hi/lo pair out.
// block 256 = 4 waves; tile M=64 x N=256 (wave owns 64 n-cols). 3-term MFMA.
// ---------------------------------------------------------------------------
__global__ __launch_bounds__(256, 2) void emb_kernel(
    const float* __restrict__ head,
    const float* __restrict__ tail,
    const float* __restrict__ Wrel,
    const float* __restrict__ brel,
    unsigned short* __restrict__ Ehi,
    unsigned short* __restrict__ Elo)
{
    __shared__ unsigned short Wth[256 * 40];   // W^T hi [n][kk]
    __shared__ unsigned short Wtl[256 * 40];   // W^T lo [n][kk]

    const int tid  = threadIdx.x;
    const int lane = tid & 63;
    const int wv   = tid >> 6;
    const int l15  = lane & 15;
    const int quad = lane >> 4;
    const long m0  = (long)blockIdx.x * 64;
    const int  n0  = wv * 64;

    floatx4 acc[4][4];
#pragma unroll
    for (int a = 0; a < 4; ++a)
#pragma unroll
        for (int bq = 0; bq < 4; ++bq) acc[a][bq] = (floatx4)(0.0f);

    const int sng = (tid & 31) * 8;      // n group (8 cols)
    const int skk = (tid >> 5) * 4;      // k sub-offset (4 rows)

    for (int ks = 0; ks < 16; ++ks) {
        __syncthreads();
        {   // stage split-transposed W_rel[k0..k0+31][0..255]
            const int k0 = ks * 32;
            unsigned short hr[4][8], lr[4][8];
#pragma unroll
            for (int r = 0; r < 4; ++r) {
                F8 fv;
                fv.v[0] = *(const float4*)(Wrel + (long)(k0 + skk + r) * 256 + sng);
                fv.v[1] = *(const float4*)(Wrel + (long)(k0 + skk + r) * 256 + sng + 4);
#pragma unroll
                for (int i = 0; i < 8; ++i) split2(fv.f[i], hr[r][i], lr[r][i]);
            }
#pragma unroll
            for (int ii = 0; ii < 8; ++ii) {
                const int i = (ii + (tid & 7)) & 7;   // rotate to break bank conflicts
                uint2 ph, pl;
                ph.x = (unsigned int)hr[0][i] | ((unsigned int)hr[1][i] << 16);
                ph.y = (unsigned int)hr[2][i] | ((unsigned int)hr[3][i] << 16);
                pl.x = (unsigned int)lr[0][i] | ((unsigned int)lr[1][i] << 16);
                pl.y = (unsigned int)lr[2][i] | ((unsigned int)lr[3][i] << 16);
                *(uint2*)&Wth[(sng + i) * 40 + skk] = ph;
                *(uint2*)&Wtl[(sng + i) * 40 + skk] = pl;
            }
        }
        __syncthreads();

        V16 ah[4], al[4];
        const int kg = ks * 32 + quad * 8;
#pragma unroll
        for (int mb = 0; mb < 4; ++mb) {
            const long row = m0 + mb * 16 + l15;
            const float* src = (kg < 256) ? (head + row * 256 + kg)
                                          : (tail + row * 256 + (kg - 256));
            F8 fv;
            fv.v[0] = *(const float4*)(src);
            fv.v[1] = *(const float4*)(src + 4);
#pragma unroll
            for (int i = 0; i < 8; ++i) split2(fv.f[i], ah[mb].s[i], al[mb].s[i]);
        }
        V16 bh[4], bl[4];
#pragma unroll
        for (int nt = 0; nt < 4; ++nt) {
            bh[nt].v = *(const int4*)&Wth[(n0 + nt * 16 + l15) * 40 + quad * 8];
            bl[nt].v = *(const int4*)&Wtl[(n0 + nt * 16 + l15) * 40 + quad * 8];
        }
#pragma unroll
        for (int mb = 0; mb < 4; ++mb)
#pragma unroll
            for (int nt = 0; nt < 4; ++nt) {
                acc[mb][nt] = __builtin_amdgcn_mfma_f32_16x16x32_bf16(ah[mb].s8, bh[nt].s8, acc[mb][nt], 0, 0, 0);
                acc[mb][nt] = __builtin_amdgcn_mfma_f32_16x16x32_bf16(al[mb].s8, bh[nt].s8, acc[mb][nt], 0, 0, 0);
                acc[mb][nt] = __builtin_amdgcn_mfma_f32_16x16x32_bf16(ah[mb].s8, bl[nt].s8, acc[mb][nt], 0, 0, 0);
            }
    }

    float bias[4];
#pragma unroll
    for (int nt = 0; nt < 4; ++nt) bias[nt] = brel[n0 + nt * 16 + l15];
#pragma unroll
    for (int mb = 0; mb < 4; ++mb)
#pragma unroll
        for (int nt = 0; nt < 4; ++nt)
#pragma unroll
            for (int r = 0; r < 4; ++r) {
                const long row = m0 + mb * 16 + quad * 4 + r;
                const float y = acc[mb][nt][r] + bias[nt];
                unsigned short h, l;
                split2(y, h, l);
                Ehi[row * 256 + n0 + nt * 16 + l15] = h;
                Elo[row * 256 + n0 + nt * 16 + l15] = l;
            }
}

// ---------------------------------------------------------------------------
// Fused flash attention + grouped class sums. grid (16 q-tiles, 8 b, nsplit).
// S^T = (c_hi+c_lo)·(q_hi+q_lo)^T  (3-term) in C/D layout (col=lane&15=q);
// online softmax per q; P via per-wave LDS into A layout; P@[c_hi|onehot].
// ---------------------------------------------------------------------------
__global__ __launch_bounds__(256, 2) void attn_kernel(
    const unsigned short* __restrict__ qhi,
    const unsigned short* __restrict__ qlo,
    const unsigned short* __restrict__ chi,
    const unsigned short* __restrict__ clo,
    const int*            __restrict__ labels,
    const float*          __restrict__ maskp,
    float* __restrict__ Opart,   // [nsplit*8192][288]
    float* __restrict__ Mst,     // [nsplit*8192]
    float* __restrict__ Lst,     // [nsplit*8192]
    int jtiles)
{
    __shared__ unsigned short cNh[32 * 264];    // c hi natural [j][d]
    __shared__ unsigned short cNl[32 * 264];    // c lo natural [j][d]
    __shared__ unsigned short cTh[288 * 40];    // c hi transposed [d][j] + onehot rows 256..287
    __shared__ unsigned short Pw[4][16 * 40];   // per-wave P [q][j]
    __shared__ float mf[32];

    const int tid  = threadIdx.x;
    const int lane = tid & 63;
    const int wv   = tid >> 6;
    const int l15  = lane & 15;
    const int quad = lane >> 4;

    const int qt = blockIdx.x;
    const int b  = blockIdx.y;
    const int sp = blockIdx.z;
    const int q0 = qt * 64;

    V16 qfh[8], qfl[8];   // q fragments (B operand), preloaded once
    {
        const long qrow = (long)b * WNQ + q0 + wv * 16 + l15;
#pragma unroll
        for (int ks = 0; ks < 8; ++ks) {
            qfh[ks].v = *(const int4*)(qhi + qrow * 256 + ks * 32 + quad * 8);
            qfl[ks].v = *(const int4*)(qlo + qrow * 256 + ks * 32 + quad * 8);
        }
    }

    floatx4 O[18];
#pragma unroll
    for (int i = 0; i < 18; ++i) O[i] = (floatx4)(0.0f);
    float m_run = -INFINITY, l_run = 0.f;

    const int dg  = tid & 31;     // d-group of 8 (also class idx for onehot)
    const int jq  = tid >> 5;     // 0..7
    const int j0s = jq * 4;

    for (int it = 0; it < jtiles; ++it) {
        const int jb = sp * (jtiles * 32) + it * 32;
        __syncthreads();
        {   // ---- stage c tile ----
            const long cbase = ((long)b * WNC + jb) * 256;
            V16 h0, h1, h2, h3;
            h0.v = *(const int4*)(chi + cbase + (j0s + 0) * 256 + dg * 8);
            h1.v = *(const int4*)(chi + cbase + (j0s + 1) * 256 + dg * 8);
            h2.v = *(const int4*)(chi + cbase + (j0s + 2) * 256 + dg * 8);
            h3.v = *(const int4*)(chi + cbase + (j0s + 3) * 256 + dg * 8);
            *(int4*)&cNh[(j0s + 0) * 264 + dg * 8] = h0.v;
            *(int4*)&cNh[(j0s + 1) * 264 + dg * 8] = h1.v;
            *(int4*)&cNh[(j0s + 2) * 264 + dg * 8] = h2.v;
            *(int4*)&cNh[(j0s + 3) * 264 + dg * 8] = h3.v;
            V16 l0, l1, l2, l3;
            l0.v = *(const int4*)(clo + cbase + (j0s + 0) * 256 + dg * 8);
            l1.v = *(const int4*)(clo + cbase + (j0s + 1) * 256 + dg * 8);
            l2.v = *(const int4*)(clo + cbase + (j0s + 2) * 256 + dg * 8);
            l3.v = *(const int4*)(clo + cbase + (j0s + 3) * 256 + dg * 8);
            *(int4*)&cNl[(j0s + 0) * 264 + dg * 8] = l0.v;
            *(int4*)&cNl[(j0s + 1) * 264 + dg * 8] = l1.v;
            *(int4*)&cNl[(j0s + 2) * 264 + dg * 8] = l2.v;
            *(int4*)&cNl[(j0s + 3) * 264 + dg * 8] = l3.v;
#pragma unroll
            for (int ii = 0; ii < 8; ++ii) {
                const int i = (ii + (tid & 7)) & 7;
                uint2 p;
                p.x = (unsigned int)h0.s[i] | ((unsigned int)h1.s[i] << 16);
                p.y = (unsigned int)h2.s[i] | ((unsigned int)h3.s[i] << 16);
                *(uint2*)&cTh[(dg * 8 + i) * 40 + j0s] = p;
            }
            // onehot rows: cTh[256+c][j] = (label[j]==c) as bf16 1.0
            const int4 lb = *(const int4*)(labels + (long)b * WNC + jb + j0s);
            const int* lbp = (const int*)&lb;
            uint2 oh;
            oh.x = ((lbp[0] == dg) ? 0x3F80u : 0u) | (((lbp[1] == dg) ? 0x3F80u : 0u) << 16);
            oh.y = ((lbp[2] == dg) ? 0x3F80u : 0u) | (((lbp[3] == dg) ? 0x3F80u : 0u) << 16);
            *(uint2*)&cTh[(256 + dg) * 40 + j0s] = oh;
            if (tid < 8)
                *(float4*)&mf[tid * 4] = *(const float4*)(maskp + (long)b * WNC + jb + tid * 4);
        }
        __syncthreads();

        // ---- S^T: 3-term split-precision MFMA ----
        floatx4 accS[2];
        accS[0] = (floatx4)(0.0f); accS[1] = (floatx4)(0.0f);
#pragma unroll
        for (int ks = 0; ks < 8; ++ks) {
            V16 ah0, al0, ah1, al1;
            ah0.v = *(const int4*)&cNh[(l15)      * 264 + ks * 32 + quad * 8];
            al0.v = *(const int4*)&cNl[(l15)      * 264 + ks * 32 + quad * 8];
            ah1.v = *(const int4*)&cNh[(16 + l15) * 264 + ks * 32 + quad * 8];
            al1.v = *(const int4*)&cNl[(16 + l15) * 264 + ks * 32 + quad * 8];
            accS[0] = __builtin_amdgcn_mfma_f32_16x16x32_bf16(ah0.s8, qfh[ks].s8, accS[0], 0, 0, 0);
            accS[0] = __builtin_amdgcn_mfma_f32_16x16x32_bf16(al0.s8, qfh[ks].s8, accS[0], 0, 0, 0);
            accS[0] = __builtin_amdgcn_mfma_f32_16x16x32_bf16(ah0.s8, qfl[ks].s8, accS[0], 0, 0, 0);
            accS[1] = __builtin_amdgcn_mfma_f32_16x16x32_bf16(ah1.s8, qfh[ks].s8, accS[1], 0, 0, 0);
            accS[1] = __builtin_amdgcn_mfma_f32_16x16x32_bf16(al1.s8, qfh[ks].s8, accS[1], 0, 0, 0);
            accS[1] = __builtin_amdgcn_mfma_f32_16x16x32_bf16(ah1.s8, qfl[ks].s8, accS[1], 0, 0, 0);
        }
#pragma unroll
        for (int jf = 0; jf < 2; ++jf)
#pragma unroll
            for (int r = 0; r < 4; ++r) accS[jf][r] *= mf[jf * 16 + quad * 4 + r];

        // ---- online softmax per q = lane&15 ----
        float v = fmaxf(fmaxf(fmaxf(accS[0][0], accS[0][1]), fmaxf(accS[0][2], accS[0][3])),
                        fmaxf(fmaxf(accS[1][0], accS[1][1]), fmaxf(accS[1][2], accS[1][3])));
        v = fmaxf(v, __shfl_xor(v, 16, 64));
        v = fmaxf(v, __shfl_xor(v, 32, 64));
        const float m_new = fmaxf(m_run, v);
        const float alpha = __expf(m_run - m_new);   // exp(-inf)=0 on first iter
        float p[8]; float ts = 0.f;
#pragma unroll
        for (int jf = 0; jf < 2; ++jf)
#pragma unroll
            for (int r = 0; r < 4; ++r) {
                const float e = __expf(accS[jf][r] - m_new);
                p[jf * 4 + r] = e; ts += e;
            }
        ts += __shfl_xor(ts, 16, 64);
        ts += __shfl_xor(ts, 32, 64);
        l_run = l_run * alpha + ts;
        m_run = m_new;

        float ar[4];
#pragma unroll
        for (int r = 0; r < 4; ++r) ar[r] = __shfl(alpha, quad * 4 + r, 64);
#pragma unroll
        for (int f = 0; f < 18; ++f)
#pragma unroll
            for (int r = 0; r < 4; ++r) O[f][r] *= ar[r];

        // ---- P (C/D layout) -> per-wave LDS in A layout [q][j] ----
#pragma unroll
        for (int jf = 0; jf < 2; ++jf) {
            uint2 w;
            w.x = (unsigned int)f2bf(p[jf * 4 + 0]) | ((unsigned int)f2bf(p[jf * 4 + 1]) << 16);
            w.y = (unsigned int)f2bf(p[jf * 4 + 2]) | ((unsigned int)f2bf(p[jf * 4 + 3]) << 16);
            *(uint2*)&Pw[wv][l15 * 40 + jf * 16 + quad * 4] = w;
        }
        asm volatile("" ::: "memory");   // keep ds_write before ds_read (same wave)

        // ---- O += P @ [c_hi | onehot] ----
        V16 pf;
        pf.v = *(const int4*)&Pw[wv][l15 * 40 + quad * 8];
#pragma unroll
        for (int dt = 0; dt < 18; ++dt) {
            V16 bfr;
            bfr.v = *(const int4*)&cTh[(dt * 16 + l15) * 40 + quad * 8];
            O[dt] = __builtin_amdgcn_mfma_f32_16x16x32_bf16(pf.s8, bfr.s8, O[dt], 0, 0, 0);
        }
    }

    {   // ---- store unnormalized partials + stats ----
        const long orow0 = (long)(sp * WB + b) * WNQ + q0 + wv * 16;
#pragma unroll
        for (int dt = 0; dt < 18; ++dt)
#pragma unroll
            for (int r = 0; r < 4; ++r)
                Opart[(orow0 + quad * 4 + r) * 288 + dt * 16 + l15] = O[dt][r];
        if (lane < 16) {
            const long sidx = (long)(sp * WB + b) * WNQ + q0 + wv * 16 + lane;
            Mst[sidx] = m_run;
            Lst[sidx] = l_run;
        }
    }
}

// ---------------------------------------------------------------------------
// Combine splits + gen head + copy gate + logaddexp. One wave per (b,q) row.
// ---------------------------------------------------------------------------
__global__ __launch_bounds__(64) void final_kernel(
    const unsigned short* __restrict__ qhi,
    const unsigned short* __restrict__ qlo,
    const float* __restrict__ Opart,
    const float* __restrict__ Mst,
    const float* __restrict__ Lst,
    const float* __restrict__ Wgen,
    const float* __restrict__ bgen,
    const float* __restrict__ Wcp,
    const float* __restrict__ bcp,
    float* __restrict__ outp,
    int ns)
{
    __shared__ float qrowF[256];
    __shared__ float gArr[32];
    __shared__ float cdArr[32];

    const int row  = blockIdx.x;       // 0..8191
    const int lane = threadIdx.x;      // 0..63

    float mstar = -INFINITY;
    for (int s = 0; s < ns; ++s) mstar = fmaxf(mstar, Mst[(long)s * NROWS + row]);
    float wgt[4]; float L = 0.f;
    for (int s = 0; s < ns; ++s) {
        const float m = Mst[(long)s * NROWS + row];
        wgt[s] = (m == -INFINITY) ? 0.f : __expf(m - mstar);
        L += Lst[(long)s * NROWS + row] * wgt[s];
    }

    const int d0 = lane * 4;
    float ctx[4] = {0.f, 0.f, 0.f, 0.f};
    for (int s = 0; s < ns; ++s) {
        const float4 o = *(const float4*)&Opart[((long)s * NROWS + row) * 288 + d0];
        ctx[0] += wgt[s] * o.x; ctx[1] += wgt[s] * o.y;
        ctx[2] += wgt[s] * o.z; ctx[3] += wgt[s] * o.w;
    }

    float qv[4];
    {
        const uint2 qa = *(const uint2*)(qhi + (long)row * 256 + d0);
        const uint2 qb = *(const uint2*)(qlo + (long)row * 256 + d0);
        qv[0] = bf2f((unsigned short)(qa.x & 0xFFFFu)) + bf2f((unsigned short)(qb.x & 0xFFFFu));
        qv[1] = bf2f((unsigned short)(qa.x >> 16))     + bf2f((unsigned short)(qb.x >> 16));
        qv[2] = bf2f((unsigned short)(qa.y & 0xFFFFu)) + bf2f((unsigned short)(qb.y & 0xFFFFu));
        qv[3] = bf2f((unsigned short)(qa.y >> 16))     + bf2f((unsigned short)(qb.y >> 16));
    }
    *(float4*)&qrowF[d0] = make_float4(qv[0], qv[1], qv[2], qv[3]);

    float cls[4] = {0.f, 0.f, 0.f, 0.f};
    if (lane < 8) {
        for (int s = 0; s < ns; ++s) {
            const float4 o = *(const float4*)&Opart[((long)s * NROWS + row) * 288 + 256 + lane * 4];
            cls[0] += wgt[s] * o.x; cls[1] += wgt[s] * o.y;
            cls[2] += wgt[s] * o.z; cls[3] += wgt[s] * o.w;
        }
    }
    __syncthreads();

    // gen logits: lanes 0..24, one class each
    float g = -INFINITY;
    if (lane < 25) {
        g = bgen[lane];
        for (int d = 0; d < 256; ++d)
            g += qrowF[d] * Wgen[d * 25 + lane];
    }
    float mg = g;
#pragma unroll
    for (int off = 32; off >= 1; off >>= 1) mg = fmaxf(mg, __shfl_xor(mg, off, 64));
    float se = (lane < 25) ? __expf(g - mg) : 0.f;
#pragma unroll
    for (int off = 32; off >= 1; off >>= 1) se += __shfl_xor(se, off, 64);
    const float glsm = g - mg - logf(se);

    // copy gate logit
    const float invL = 1.f / L;
    float part = 0.f;
#pragma unroll
    for (int i = 0; i < 4; ++i)
        part += qv[i] * Wcp[d0 + i] + ctx[i] * invL * Wcp[256 + d0 + i];
#pragma unroll
    for (int off = 32; off >= 1; off >>= 1) part += __shfl_xor(part, off, 64);
    const float logit = part + bcp[0];

    const float lscp  = logsig(logit);
    const float lsgen = logsig(-logit);
    const float logL  = logf(L);

    if (lane < 8) {
#pragma unroll
        for (int i = 0; i < 4; ++i)
            cdArr[lane * 4 + i] = (cls[i] > 0.f) ? (logf(cls[i]) - logL) : -INFINITY;
    }
    if (lane < 25) gArr[lane] = glsm;
    __syncthreads();

    if (lane < 25) {
        const float a  = lscp + cdArr[lane];
        const float bb = lsgen + gArr[lane];
        const float mx = fmaxf(a, bb);
        const float o  = (mx == -INFINITY) ? -INFINITY
                         : mx + log1pf(__expf(fminf(a, bb) - mx));
        outp[(long)row * 25 + lane] = o;
    }
}

// ---------------------------------------------------------------------------
extern "C" void kernel_launch(void* const* d_in, const int* in_sizes, int n_in,
                              void* d_out, int out_size, void* d_ws, size_t ws_size,
                              hipStream_t stream) {
    const float* q_head = (const float*)d_in[0];
    const float* q_tail = (const float*)d_in[1];
    const float* c_head = (const float*)d_in[2];
    const float* c_tail = (const float*)d_in[3];
    const int*   labels = (const int*)d_in[4];
    const float* maskp  = (const float*)d_in[5];
    const float* Wrel   = (const float*)d_in[6];
    const float* brel   = (const float*)d_in[7];
    const float* Wgen   = (const float*)d_in[8];
    const float* bgen   = (const float*)d_in[9];
    const float* Wcp    = (const float*)d_in[10];
    const float* bcp    = (const float*)d_in[11];

    // nsplit chosen by workspace size (deterministic per-process => graph-safe)
    auto need = [](long ns) -> long {
        return 41943040l + ns * (9437184l + 65536l);
    };
    int ns = 4;
    if ((long)ws_size < need(4)) ns = 2;
    if ((long)ws_size < need(2)) ns = 1;
    const int jtiles = 128 / ns;

    char* ws = (char*)d_ws;
    unsigned short* qhi = (unsigned short*)(ws);                    //  4 MB
    unsigned short* qlo = (unsigned short*)(ws + 4194304l);         //  4 MB
    unsigned short* chi = (unsigned short*)(ws + 8388608l);         // 16 MB
    unsigned short* clo = (unsigned short*)(ws + 25165824l);        // 16 MB
    float* Opart = (float*)(ws + 41943040l);                        // ns*9 MB
    float* Mst   = (float*)(ws + 41943040l + (long)ns * 9437184l);
    float* Lst   = Mst + (long)ns * NROWS;

    hipLaunchKernelGGL(emb_kernel, dim3(128), dim3(256), 0, stream,
                       q_head, q_tail, Wrel, brel, qhi, qlo);
    hipLaunchKernelGGL(emb_kernel, dim3(512), dim3(256), 0, stream,
                       c_head, c_tail, Wrel, brel, chi, clo);
    hipLaunchKernelGGL(attn_kernel, dim3(16, 8, ns), dim3(256), 0, stream,
                       qhi, qlo, chi, clo, labels, maskp, Opart, Mst, Lst, jtiles);
    hipLaunchKernelGGL(final_kernel, dim3(NROWS), dim3(64), 0, stream,
                       qhi, qlo, Opart, Mst, Lst, Wgen, bgen, Wcp, bcp,
                       (float*)d_out, ns);
}

// Round 3
// 359.083 us; speedup vs baseline: 2.7422x; 2.7422x over previous
//
#include <hip/hip_runtime.h>

// B=8, NQ=1024, NC=4096, D=256, C+1=25. FP32 I/O; labels int32.
// Split-precision bf16 MFMA (hi+lo, 3-term) for emb GEMM and QK^T;
// single bf16 MFMA for P@[c_emb|onehot]. Flash online softmax, nc-split.

typedef __attribute__((ext_vector_type(8))) short short8;
typedef __attribute__((ext_vector_type(4))) float floatx4;

#define WB 8
#define WNQ 1024
#define WNC 4096
#define NROWS 8192          // B*NQ

static __device__ __forceinline__ float bf2f(unsigned short u) {
    union { unsigned int i; float f; } v; v.i = ((unsigned int)u) << 16; return v.f;
}
static __device__ __forceinline__ unsigned short f2bf(float f) {
    union { float ff; unsigned int i; } v; v.ff = f;
    return (unsigned short)((v.i + 0x7FFFu + ((v.i >> 16) & 1u)) >> 16);
}
static __device__ __forceinline__ void split2(float x, unsigned short& h, unsigned short& l) {
    h = f2bf(x);
    l = f2bf(x - bf2f(h));
}
static __device__ __forceinline__ float logsig(float x) {
    return (x >= 0.f) ? -log1pf(__expf(-x)) : x - log1pf(__expf(x));
}

union V16 { int4 v; short8 s8; unsigned short s[8]; uint2 u2[2]; };
union F8  { float4 v[2]; float f[8]; };

// ---------------------------------------------------------------------------
// Pre-split W_rel (fp32 [512][256]) into n-major bf16 hi/lo [256][512].
// ---------------------------------------------------------------------------
__global__ void wprep_kernel(const float* __restrict__ Wrel,
                             unsigned short* __restrict__ WTh,
                             unsigned short* __restrict__ WTl)
{
    const int n = blockIdx.x;
    for (int k = threadIdx.x; k < 512; k += 256) {
        const float w = Wrel[(long)k * 256 + n];
        unsigned short h, l;
        split2(w, h, l);
        WTh[(long)n * 512 + k] = h;
        WTl[(long)n * 512 + k] = l;
    }
}

// ---------------------------------------------------------------------------
// emb = concat(head,tail) @ W_rel + b_rel -> bf16 hi/lo. LDS-free.
// Blocks 0..127 -> q rows, 128..639 -> c rows. 4 waves; wave owns 64 n-cols.
// B fragments loaded straight from WTh/WTl (L2-resident, 64B-line friendly).
// ---------------------------------------------------------------------------
__global__ __launch_bounds__(256, 2) void emb_kernel(
    const float* __restrict__ q_head, const float* __restrict__ q_tail,
    const float* __restrict__ c_head, const float* __restrict__ c_tail,
    const unsigned short* __restrict__ WTh,
    const unsigned short* __restrict__ WTl,
    const float* __restrict__ brel,
    unsigned short* __restrict__ Qhi, unsigned short* __restrict__ Qlo,
    unsigned short* __restrict__ Chi, unsigned short* __restrict__ Clo)
{
    const int tid  = threadIdx.x;
    const int lane = tid & 63;
    const int wv   = tid >> 6;
    const int l15  = lane & 15;
    const int quad = lane >> 4;
    const int n0   = wv * 64;

    const float* head; const float* tail;
    unsigned short* Ehi; unsigned short* Elo;
    long m0;
    if (blockIdx.x < 128) {
        head = q_head; tail = q_tail; Ehi = Qhi; Elo = Qlo;
        m0 = (long)blockIdx.x * 64;
    } else {
        head = c_head; tail = c_tail; Ehi = Chi; Elo = Clo;
        m0 = (long)(blockIdx.x - 128) * 64;
    }

    floatx4 acc[4][4];
#pragma unroll
    for (int a = 0; a < 4; ++a)
#pragma unroll
        for (int bq = 0; bq < 4; ++bq) acc[a][bq] = (floatx4)(0.0f);

    for (int ks = 0; ks < 16; ++ks) {
        const int kg = ks * 32 + quad * 8;   // wave-uniform head/tail select per ks
        const float* srcb = (kg < 256) ? (head + kg) : (tail + (kg - 256));

        V16 bh[4], bl[4];
#pragma unroll
        for (int nt = 0; nt < 4; ++nt) {
            const long wb = (long)(n0 + nt * 16 + l15) * 512 + ks * 32 + quad * 8;
            bh[nt].v = *(const int4*)(WTh + wb);
            bl[nt].v = *(const int4*)(WTl + wb);
        }

        V16 ah[4], al[4];
#pragma unroll
        for (int mb = 0; mb < 4; ++mb) {
            const long row = m0 + mb * 16 + l15;
            F8 fv;
            fv.v[0] = *(const float4*)(srcb + row * 256);
            fv.v[1] = *(const float4*)(srcb + row * 256 + 4);
#pragma unroll
            for (int i = 0; i < 8; ++i) split2(fv.f[i], ah[mb].s[i], al[mb].s[i]);
        }
#pragma unroll
        for (int mb = 0; mb < 4; ++mb)
#pragma unroll
            for (int nt = 0; nt < 4; ++nt) {
                acc[mb][nt] = __builtin_amdgcn_mfma_f32_16x16x32_bf16(ah[mb].s8, bh[nt].s8, acc[mb][nt], 0, 0, 0);
                acc[mb][nt] = __builtin_amdgcn_mfma_f32_16x16x32_bf16(al[mb].s8, bh[nt].s8, acc[mb][nt], 0, 0, 0);
                acc[mb][nt] = __builtin_amdgcn_mfma_f32_16x16x32_bf16(ah[mb].s8, bl[nt].s8, acc[mb][nt], 0, 0, 0);
            }
    }

    float bias[4];
#pragma unroll
    for (int nt = 0; nt < 4; ++nt) bias[nt] = brel[n0 + nt * 16 + l15];
#pragma unroll
    for (int mb = 0; mb < 4; ++mb)
#pragma unroll
        for (int nt = 0; nt < 4; ++nt)
#pragma unroll
            for (int r = 0; r < 4; ++r) {
                const long row = m0 + mb * 16 + quad * 4 + r;
                const float y = acc[mb][nt][r] + bias[nt];
                unsigned short h, l;
                split2(y, h, l);
                Ehi[row * 256 + n0 + nt * 16 + l15] = h;
                Elo[row * 256 + n0 + nt * 16 + l15] = l;
            }
}

// ---------------------------------------------------------------------------
// Fused flash attention + grouped class sums. grid (16 q-tiles, 8 b, nsplit).
// cTh layout: row d (stride 40 shorts), 8B j-slots XOR-swizzled by (d>>3)&7:
// writes ~4-way instead of 32-way; reads via two swizzled ds_read_b64.
// ---------------------------------------------------------------------------
__global__ __launch_bounds__(256, 2) void attn_kernel(
    const unsigned short* __restrict__ qhi,
    const unsigned short* __restrict__ qlo,
    const unsigned short* __restrict__ chi,
    const unsigned short* __restrict__ clo,
    const int*            __restrict__ labels,
    const float*          __restrict__ maskp,
    float* __restrict__ Opart,   // [nsplit*8192][288]
    float* __restrict__ Mst,     // [nsplit*8192]
    float* __restrict__ Lst,     // [nsplit*8192]
    int jtiles)
{
    __shared__ unsigned short cNh[32 * 264];    // c hi natural [j][d]
    __shared__ unsigned short cNl[32 * 264];    // c lo natural [j][d]
    __shared__ unsigned short cTh[288 * 40];    // c hi transposed [d][j-slot^swz] + onehot rows 256..287
    __shared__ unsigned short Pw[4][16 * 40];   // per-wave P [q][j]
    __shared__ float mf[32];

    const int tid  = threadIdx.x;
    const int lane = tid & 63;
    const int wv   = tid >> 6;
    const int l15  = lane & 15;
    const int quad = lane >> 4;

    const int qt = blockIdx.x;
    const int b  = blockIdx.y;
    const int sp = blockIdx.z;
    const int q0 = qt * 64;

    V16 qfh[8], qfl[8];   // q fragments (B operand), preloaded once
    {
        const long qrow = (long)b * WNQ + q0 + wv * 16 + l15;
#pragma unroll
        for (int ks = 0; ks < 8; ++ks) {
            qfh[ks].v = *(const int4*)(qhi + qrow * 256 + ks * 32 + quad * 8);
            qfl[ks].v = *(const int4*)(qlo + qrow * 256 + ks * 32 + quad * 8);
        }
    }

    floatx4 O[18];
#pragma unroll
    for (int i = 0; i < 18; ++i) O[i] = (floatx4)(0.0f);
    float m_run = -INFINITY, l_run = 0.f;

    const int dg  = tid & 31;     // d-group of 8 (also class idx for onehot)
    const int jq  = tid >> 5;     // 0..7  (8B j-slot)
    const int j0s = jq * 4;

    for (int it = 0; it < jtiles; ++it) {
        const int jb = sp * (jtiles * 32) + it * 32;
        __syncthreads();
        {   // ---- stage c tile ----
            const long cbase = ((long)b * WNC + jb) * 256;
            V16 h0, h1, h2, h3;
            h0.v = *(const int4*)(chi + cbase + (j0s + 0) * 256 + dg * 8);
            h1.v = *(const int4*)(chi + cbase + (j0s + 1) * 256 + dg * 8);
            h2.v = *(const int4*)(chi + cbase + (j0s + 2) * 256 + dg * 8);
            h3.v = *(const int4*)(chi + cbase + (j0s + 3) * 256 + dg * 8);
            *(int4*)&cNh[(j0s + 0) * 264 + dg * 8] = h0.v;
            *(int4*)&cNh[(j0s + 1) * 264 + dg * 8] = h1.v;
            *(int4*)&cNh[(j0s + 2) * 264 + dg * 8] = h2.v;
            *(int4*)&cNh[(j0s + 3) * 264 + dg * 8] = h3.v;
            V16 l0, l1, l2, l3;
            l0.v = *(const int4*)(clo + cbase + (j0s + 0) * 256 + dg * 8);
            l1.v = *(const int4*)(clo + cbase + (j0s + 1) * 256 + dg * 8);
            l2.v = *(const int4*)(clo + cbase + (j0s + 2) * 256 + dg * 8);
            l3.v = *(const int4*)(clo + cbase + (j0s + 3) * 256 + dg * 8);
            *(int4*)&cNl[(j0s + 0) * 264 + dg * 8] = l0.v;
            *(int4*)&cNl[(j0s + 1) * 264 + dg * 8] = l1.v;
            *(int4*)&cNl[(j0s + 2) * 264 + dg * 8] = l2.v;
            *(int4*)&cNl[(j0s + 3) * 264 + dg * 8] = l3.v;
            // transposed hi: static data index, swizzled address
            const int wsw = (jq ^ (dg & 7)) << 2;
#pragma unroll
            for (int i = 0; i < 8; ++i) {
                uint2 p;
                p.x = (unsigned int)h0.s[i] | ((unsigned int)h1.s[i] << 16);
                p.y = (unsigned int)h2.s[i] | ((unsigned int)h3.s[i] << 16);
                *(uint2*)&cTh[(dg * 8 + i) * 40 + wsw] = p;
            }
            // onehot rows: cTh[256+cls][j] = (label[j]==cls); row g = (256+dg)>>3 -> swz dg>>3
            const int4 lb = *(const int4*)(labels + (long)b * WNC + jb + j0s);
            const int* lbp = (const int*)&lb;
            uint2 oh;
            oh.x = ((lbp[0] == dg) ? 0x3F80u : 0u) | (((lbp[1] == dg) ? 0x3F80u : 0u) << 16);
            oh.y = ((lbp[2] == dg) ? 0x3F80u : 0u) | (((lbp[3] == dg) ? 0x3F80u : 0u) << 16);
            *(uint2*)&cTh[(256 + dg) * 40 + ((jq ^ (dg >> 3)) << 2)] = oh;
            if (tid < 8)
                *(float4*)&mf[tid * 4] = *(const float4*)(maskp + (long)b * WNC + jb + tid * 4);
        }
        __syncthreads();

        // ---- S^T: 3-term split-precision MFMA ----
        floatx4 accS[2];
        accS[0] = (floatx4)(0.0f); accS[1] = (floatx4)(0.0f);
#pragma unroll
        for (int ks = 0; ks < 8; ++ks) {
            V16 ah0, al0, ah1, al1;
            ah0.v = *(const int4*)&cNh[(l15)      * 264 + ks * 32 + quad * 8];
            al0.v = *(const int4*)&cNl[(l15)      * 264 + ks * 32 + quad * 8];
            ah1.v = *(const int4*)&cNh[(16 + l15) * 264 + ks * 32 + quad * 8];
            al1.v = *(const int4*)&cNl[(16 + l15) * 264 + ks * 32 + quad * 8];
            accS[0] = __builtin_amdgcn_mfma_f32_16x16x32_bf16(ah0.s8, qfh[ks].s8, accS[0], 0, 0, 0);
            accS[0] = __builtin_amdgcn_mfma_f32_16x16x32_bf16(al0.s8, qfh[ks].s8, accS[0], 0, 0, 0);
            accS[0] = __builtin_amdgcn_mfma_f32_16x16x32_bf16(ah0.s8, qfl[ks].s8, accS[0], 0, 0, 0);
            accS[1] = __builtin_amdgcn_mfma_f32_16x16x32_bf16(ah1.s8, qfh[ks].s8, accS[1], 0, 0, 0);
            accS[1] = __builtin_amdgcn_mfma_f32_16x16x32_bf16(al1.s8, qfh[ks].s8, accS[1], 0, 0, 0);
            accS[1] = __builtin_amdgcn_mfma_f32_16x16x32_bf16(ah1.s8, qfl[ks].s8, accS[1], 0, 0, 0);
        }
#pragma unroll
        for (int jf = 0; jf < 2; ++jf)
#pragma unroll
            for (int r = 0; r < 4; ++r) accS[jf][r] *= mf[jf * 16 + quad * 4 + r];

        // ---- online softmax per q = lane&15 ----
        float v = fmaxf(fmaxf(fmaxf(accS[0][0], accS[0][1]), fmaxf(accS[0][2], accS[0][3])),
                        fmaxf(fmaxf(accS[1][0], accS[1][1]), fmaxf(accS[1][2], accS[1][3])));
        v = fmaxf(v, __shfl_xor(v, 16, 64));
        v = fmaxf(v, __shfl_xor(v, 32, 64));
        const float m_new = fmaxf(m_run, v);
        const float alpha = __expf(m_run - m_new);   // exp(-inf)=0 on first iter
        float p[8]; float ts = 0.f;
#pragma unroll
        for (int jf = 0; jf < 2; ++jf)
#pragma unroll
            for (int r = 0; r < 4; ++r) {
                const float e = __expf(accS[jf][r] - m_new);
                p[jf * 4 + r] = e; ts += e;
            }
        ts += __shfl_xor(ts, 16, 64);
        ts += __shfl_xor(ts, 32, 64);
        l_run = l_run * alpha + ts;
        m_run = m_new;

        float ar[4];
#pragma unroll
        for (int r = 0; r < 4; ++r) ar[r] = __shfl(alpha, quad * 4 + r, 64);
#pragma unroll
        for (int f = 0; f < 18; ++f)
#pragma unroll
            for (int r = 0; r < 4; ++r) O[f][r] *= ar[r];

        // ---- P (C/D layout) -> per-wave LDS in A layout [q][j] ----
#pragma unroll
        for (int jf = 0; jf < 2; ++jf) {
            uint2 w;
            w.x = (unsigned int)f2bf(p[jf * 4 + 0]) | ((unsigned int)f2bf(p[jf * 4 + 1]) << 16);
            w.y = (unsigned int)f2bf(p[jf * 4 + 2]) | ((unsigned int)f2bf(p[jf * 4 + 3]) << 16);
            *(uint2*)&Pw[wv][l15 * 40 + jf * 16 + quad * 4] = w;
        }
        asm volatile("" ::: "memory");   // keep ds_write before ds_read (same wave)

        // ---- O += P @ [c_hi | onehot] ----
        V16 pf;
        pf.v = *(const int4*)&Pw[wv][l15 * 40 + quad * 8];
#pragma unroll
        for (int dt = 0; dt < 18; ++dt) {
            const int d   = dt * 16 + l15;
            const int sw  = (d >> 3) & 7;
            const int rb  = d * 40;
            V16 bfr;
            bfr.u2[0] = *(const uint2*)&cTh[rb + (((2 * quad)     ^ sw) << 2)];
            bfr.u2[1] = *(const uint2*)&cTh[rb + (((2 * quad + 1) ^ sw) << 2)];
            O[dt] = __builtin_amdgcn_mfma_f32_16x16x32_bf16(pf.s8, bfr.s8, O[dt], 0, 0, 0);
        }
    }

    {   // ---- store unnormalized partials + stats ----
        const long orow0 = (long)(sp * WB + b) * WNQ + q0 + wv * 16;
#pragma unroll
        for (int dt = 0; dt < 18; ++dt)
#pragma unroll
            for (int r = 0; r < 4; ++r)
                Opart[(orow0 + quad * 4 + r) * 288 + dt * 16 + l15] = O[dt][r];
        if (lane < 16) {
            const long sidx = (long)(sp * WB + b) * WNQ + q0 + wv * 16 + lane;
            Mst[sidx] = m_run;
            Lst[sidx] = l_run;
        }
    }
}

// ---------------------------------------------------------------------------
// Combine splits + gen head + copy gate + logaddexp. One wave per (b,q) row.
// ---------------------------------------------------------------------------
__global__ __launch_bounds__(64) void final_kernel(
    const unsigned short* __restrict__ qhi,
    const unsigned short* __restrict__ qlo,
    const float* __restrict__ Opart,
    const float* __restrict__ Mst,
    const float* __restrict__ Lst,
    const float* __restrict__ Wgen,
    const float* __restrict__ bgen,
    const float* __restrict__ Wcp,
    const float* __restrict__ bcp,
    float* __restrict__ outp,
    int ns)
{
    __shared__ float qrowF[256];
    __shared__ float gArr[32];
    __shared__ float cdArr[32];

    const int row  = blockIdx.x;       // 0..8191
    const int lane = threadIdx.x;      // 0..63

    float ms[4];
#pragma unroll
    for (int s = 0; s < 4; ++s) ms[s] = (s < ns) ? Mst[(long)s * NROWS + row] : -INFINITY;
    const float mstar = fmaxf(fmaxf(ms[0], ms[1]), fmaxf(ms[2], ms[3]));
    float wgt[4]; float L = 0.f;
#pragma unroll
    for (int s = 0; s < 4; ++s) {
        wgt[s] = (ms[s] == -INFINITY) ? 0.f : __expf(ms[s] - mstar);
        if (s < ns) L += Lst[(long)s * NROWS + row] * wgt[s];
    }

    const int d0 = lane * 4;
    float ctx[4] = {0.f, 0.f, 0.f, 0.f};
#pragma unroll
    for (int s = 0; s < 4; ++s) {
        if (s < ns) {
            const float4 o = *(const float4*)&Opart[((long)s * NROWS + row) * 288 + d0];
            ctx[0] += wgt[s] * o.x; ctx[1] += wgt[s] * o.y;
            ctx[2] += wgt[s] * o.z; ctx[3] += wgt[s] * o.w;
        }
    }

    float qv[4];
    {
        const uint2 qa = *(const uint2*)(qhi + (long)row * 256 + d0);
        const uint2 qb = *(const uint2*)(qlo + (long)row * 256 + d0);
        qv[0] = bf2f((unsigned short)(qa.x & 0xFFFFu)) + bf2f((unsigned short)(qb.x & 0xFFFFu));
        qv[1] = bf2f((unsigned short)(qa.x >> 16))     + bf2f((unsigned short)(qb.x >> 16));
        qv[2] = bf2f((unsigned short)(qa.y & 0xFFFFu)) + bf2f((unsigned short)(qb.y & 0xFFFFu));
        qv[3] = bf2f((unsigned short)(qa.y >> 16))     + bf2f((unsigned short)(qb.y >> 16));
    }
    *(float4*)&qrowF[d0] = make_float4(qv[0], qv[1], qv[2], qv[3]);

    float cls[4] = {0.f, 0.f, 0.f, 0.f};
    if (lane < 8) {
#pragma unroll
        for (int s = 0; s < 4; ++s) {
            if (s < ns) {
                const float4 o = *(const float4*)&Opart[((long)s * NROWS + row) * 288 + 256 + lane * 4];
                cls[0] += wgt[s] * o.x; cls[1] += wgt[s] * o.y;
                cls[2] += wgt[s] * o.z; cls[3] += wgt[s] * o.w;
            }
        }
    }
    __syncthreads();

    // gen logits: lanes 0..24, one class each
    float g = -INFINITY;
    if (lane < 25) {
        g = bgen[lane];
        for (int d = 0; d < 256; ++d)
            g += qrowF[d] * Wgen[d * 25 + lane];
    }
    float mg = g;
#pragma unroll
    for (int off = 32; off >= 1; off >>= 1) mg = fmaxf(mg, __shfl_xor(mg, off, 64));
    float se = (lane < 25) ? __expf(g - mg) : 0.f;
#pragma unroll
    for (int off = 32; off >= 1; off >>= 1) se += __shfl_xor(se, off, 64);
    const float glsm = g - mg - logf(se);

    // copy gate logit
    const float invL = 1.f / L;
    float part = 0.f;
#pragma unroll
    for (int i = 0; i < 4; ++i)
        part += qv[i] * Wcp[d0 + i] + ctx[i] * invL * Wcp[256 + d0 + i];
#pragma unroll
    for (int off = 32; off >= 1; off >>= 1) part += __shfl_xor(part, off, 64);
    const float logit = part + bcp[0];

    const float lscp  = logsig(logit);
    const float lsgen = logsig(-logit);
    const float logL  = logf(L);

    if (lane < 8) {
#pragma unroll
        for (int i = 0; i < 4; ++i)
            cdArr[lane * 4 + i] = (cls[i] > 0.f) ? (logf(cls[i]) - logL) : -INFINITY;
    }
    if (lane < 25) gArr[lane] = glsm;
    __syncthreads();

    if (lane < 25) {
        const float a  = lscp + cdArr[lane];
        const float bb = lsgen + gArr[lane];
        const float mx = fmaxf(a, bb);
        const float o  = (mx == -INFINITY) ? -INFINITY
                         : mx + log1pf(__expf(fminf(a, bb) - mx));
        outp[(long)row * 25 + lane] = o;
    }
}

// ---------------------------------------------------------------------------
extern "C" void kernel_launch(void* const* d_in, const int* in_sizes, int n_in,
                              void* d_out, int out_size, void* d_ws, size_t ws_size,
                              hipStream_t stream) {
    const float* q_head = (const float*)d_in[0];
    const float* q_tail = (const float*)d_in[1];
    const float* c_head = (const float*)d_in[2];
    const float* c_tail = (const float*)d_in[3];
    const int*   labels = (const int*)d_in[4];
    const float* maskp  = (const float*)d_in[5];
    const float* Wrel   = (const float*)d_in[6];
    const float* brel   = (const float*)d_in[7];
    const float* Wgen   = (const float*)d_in[8];
    const float* bgen   = (const float*)d_in[9];
    const float* Wcp    = (const float*)d_in[10];
    const float* bcp    = (const float*)d_in[11];

    // nsplit chosen by workspace size (deterministic => graph-safe)
    auto need = [](long ns) -> long {
        return 42991616l + ns * (9437184l + 65536l);
    };
    int ns = 4;
    if ((long)ws_size < need(4)) ns = 2;
    if ((long)ws_size < need(2)) ns = 1;
    const int jtiles = 128 / ns;

    char* ws = (char*)d_ws;
    unsigned short* qhi = (unsigned short*)(ws);                    //  4 MB
    unsigned short* qlo = (unsigned short*)(ws + 4194304l);         //  4 MB
    unsigned short* chi = (unsigned short*)(ws + 8388608l);         // 16 MB
    unsigned short* clo = (unsigned short*)(ws + 25165824l);        // 16 MB
    unsigned short* WTh = (unsigned short*)(ws + 41943040l);        // 256 KB
    unsigned short* WTl = (unsigned short*)(ws + 42467328l);        // 256 KB
    float* Opart = (float*)(ws + 42991616l);                        // ns*9 MB
    float* Mst   = (float*)(ws + 42991616l + (long)ns * 9437184l);
    float* Lst   = Mst + (long)ns * NROWS;

    hipLaunchKernelGGL(wprep_kernel, dim3(256), dim3(256), 0, stream,
                       Wrel, WTh, WTl);
    hipLaunchKernelGGL(emb_kernel, dim3(640), dim3(256), 0, stream,
                       q_head, q_tail, c_head, c_tail, WTh, WTl, brel,
                       qhi, qlo, chi, clo);
    hipLaunchKernelGGL(attn_kernel, dim3(16, 8, ns), dim3(256), 0, stream,
                       qhi, qlo, chi, clo, labels, maskp, Opart, Mst, Lst, jtiles);
    hipLaunchKernelGGL(final_kernel, dim3(NROWS), dim3(64), 0, stream,
                       qhi, qlo, Opart, Mst, Lst, Wgen, bgen, Wcp, bcp,
                       (float*)d_out, ns);
}